// Round 1
// baseline (458.277 us; speedup 1.0000x reference)
//
#include <hip/hip_runtime.h>

// Problem constants (shapes fixed by setup_inputs): nw_out [N=4, C=19, H=512, W=1024] fp32.
#define N_IMG 4
#define C_CLS 19
#define HW    (512 * 1024)          // per-image, per-channel plane
#define NPIX  (N_IMG * HW)          // 2,097,152 pixels
#define VPIX  (NPIX / 4)            // 524,288 float4 pixel-groups
#define NBLK  (VPIX / 256)          // 2,048 blocks -> exactly 8 blocks/CU on 256 CUs
#define IW    0.2f

typedef float f4 __attribute__((ext_vector_type(4)));

// ws layout: [0..18] gsum, [19..37] gcnt, [38] ticket (as unsigned)
// ---------------------------------------------------------------------------
// Kernel 1: zero the 39-float workspace header (harness poisons d_ws each call).
// ---------------------------------------------------------------------------
__global__ void zero_ws(float* ws) {
    int t = threadIdx.x;
    if (t < 2 * C_CLS + 1) ws[t] = 0.0f;
}

// ---------------------------------------------------------------------------
// Kernel 2: fused single pass + last-block finalize.
// Streaming online softmax-of-squares: per pixel keep (m, l, q, argmax) only
// (~16 VGPRs of state vs 76 for the load-all-19 version) so we fit 8 waves/EU
// and the 18 channel loads pipeline instead of draining vmcnt(0) monolithically.
//   new max m' = max(m, x); f = e^(m-m'); e = e^(x-m')
//   l <- l*f   + e          (running sum of exp)
//   q <- q*f^2 + e^2        (running sum of exp^2)
//   s = q / l^2 = sum(prob^2)   (identical math, rescaled to final max)
// Last block to finish (device-scope ticket) computes den_c and the output,
// removing the separate finalize launch.
// ---------------------------------------------------------------------------
__global__ __launch_bounds__(256, 8) void fused_pass(const float* __restrict__ x,
                                                     float* __restrict__ ws,
                                                     float* __restrict__ out) {
    float* gsum = ws;
    float* gcnt = ws + C_CLS;

    __shared__ float s_sum[C_CLS];
    __shared__ float s_cnt[C_CLS];
    __shared__ int   s_last;

    const int t = threadIdx.x;
    if (t < C_CLS) { s_sum[t] = 0.0f; s_cnt[t] = 0.0f; }
    __syncthreads();

    // vec4 pixel-group index; grid exactly covers VPIX (2048 blocks * 256).
    const int v   = blockIdx.x * 256 + t;
    const int n   = v >> 17;                 // HW/4 = 131072 = 2^17
    const int hw4 = v & (131072 - 1);
    const float* base = x + (size_t)n * C_CLS * HW + (size_t)hw4 * 4;

    f4 m = *(const f4*)(base);               // channel 0
    f4 l = {1.0f, 1.0f, 1.0f, 1.0f};         // exp(0)
    f4 q = {1.0f, 1.0f, 1.0f, 1.0f};
    int am[4] = {0, 0, 0, 0};                // only compile-time-const indexed (reg-safe)

#pragma unroll
    for (int c = 1; c < C_CLS; ++c) {
        f4 xv = *(const f4*)(base + (size_t)c * HW);
#pragma unroll
        for (int j = 0; j < 4; ++j) {
            float xj = xv[j];
            float mo = m[j];
            float mn = fmaxf(mo, xj);
            float f  = __expf(mo - mn);      // 1.0 when max unchanged
            float e  = __expf(xj - mn);
            l[j] = l[j] * f + e;
            q[j] = q[j] * (f * f) + e * e;
            // first-max semantics (matches jnp.argmax): strict > keeps earlier index
            am[j] = (xj > mo) ? c : am[j];
            m[j]  = mn;
        }
    }

#pragma unroll
    for (int j = 0; j < 4; ++j) {
        float s = q[j] / (l[j] * l[j]);      // sum(prob^2) for this pixel
        atomicAdd(&s_sum[am[j]], s);
        atomicAdd(&s_cnt[am[j]], 1.0f);      // exact: integer-valued fp32 < 2^24
    }

    __syncthreads();
    if (t < C_CLS) {
        atomicAdd(&gsum[t], s_sum[t]);
        atomicAdd(&gcnt[t], s_cnt[t]);
    }
    __threadfence();                          // make this block's adds device-visible
    __syncthreads();

    if (t == 0) {
        unsigned* ticket = (unsigned*)(ws + 2 * C_CLS);
        unsigned old = atomicAdd(ticket, 1u); // device-scope; no dispatch-order assumption
        s_last = (old == (unsigned)(NBLK - 1)) ? 1 : 0;
    }
    __syncthreads();

    if (s_last && t < 64) {
        float vsum = 0.0f;
        if (t < C_CLS) {
            // atomic reads: L2-coherent path, immune to any stale-L1 concern
            float cnt = atomicAdd(&gcnt[t], 0.0f);
            float sm  = atomicAdd(&gsum[t], 0.0f);
            const float scale = powf((float)NPIX, 1.0f - IW);     // Np^0.8
            float den = fmaxf(powf(cnt, IW) * scale, 1.0f);
            vsum = sm / den;
        }
#pragma unroll
        for (int off = 32; off > 0; off >>= 1)
            vsum += __shfl_down(vsum, off);
        if (t == 0)
            out[0] = -vsum / (float)(N_IMG * C_CLS);
    }
}

extern "C" void kernel_launch(void* const* d_in, const int* in_sizes, int n_in,
                              void* d_out, int out_size, void* d_ws, size_t ws_size,
                              hipStream_t stream) {
    const float* x = (const float*)d_in[0];
    float* ws = (float*)d_ws;

    zero_ws<<<1, 64, 0, stream>>>(ws);
    fused_pass<<<NBLK, 256, 0, stream>>>(x, ws, (float*)d_out);
}